// Round 6
// baseline (238.656 us; speedup 1.0000x reference)
//
#include <hip/hip_runtime.h>
#include <stdint.h>

#define NNODES 200000
#define BNODES 40000
#define DEG    16
#define DFEAT  128
#define DOUT   256
#define NCLS   128
#define TILE   16   // nodes per block (4 per wave)

#define FEAT_CVT_BLOCKS 6250   // 200000*128 elems / (256 thr * 16 elems)

typedef __attribute__((ext_vector_type(8))) __bf16 bf16x8;
typedef __attribute__((ext_vector_type(4))) float  floatx4;
typedef __attribute__((ext_vector_type(2))) float  floatx2;

#if defined(__has_builtin)
#if __has_builtin(__builtin_amdgcn_cvt_pk_f32_fp8) && __has_builtin(__builtin_amdgcn_cvt_pk_fp8_f32)
#define HW_FP8 1
#endif
#endif
#ifndef HW_FP8
#define HW_FP8 0
#endif

// round-to-nearest-even fp32 -> bf16 bits
__device__ __forceinline__ uint32_t f2bf(float f) {
  uint32_t x = __float_as_uint(f);
  return ((x + 0x7fffu + ((x >> 16) & 1u)) >> 16) & 0xffffu;
}

// fp32 -> OCP e4m3fn, RTNE, saturating at 448, denormal-correct (SW fallback)
__device__ __forceinline__ uint32_t f2fp8(float f) {
  uint32_t u = __float_as_uint(f);
  uint32_t s = (u >> 24) & 0x80u;
  uint32_t a = u & 0x7fffffffu;
  if (a >= 0x43E80000u) return s | 0x7Eu;            // |x| >= 464 -> 448
  if (a < 0x3C800000u) {                             // |x| < 2^-6 -> denormal
    uint32_t q = (uint32_t)rintf(__uint_as_float(a) * 512.0f);  // RTNE, 0..8
    return s | q;                                    // q==8 == 2^-6 exactly
  }
  uint32_t r = a + 0x7FFFFu + ((a >> 20) & 1u);      // RTNE into 3-bit mantissa
  return s | ((r >> 20) - (120u << 3));              // ((e8-120)<<3)|m3
}

// e4m3fn byte -> f32 (SW fallback): exponent re-bias via *2^120
__device__ __forceinline__ float fp82f(uint32_t b) {
  uint32_t x = ((b & 0x80u) << 24) | ((b & 0x7Fu) << 20);
  return __uint_as_float(x) * __uint_as_float(0x7B800000u);   // * 2^120
}

// 4 fp32 -> packed fp8 dword (HW v_cvt_pk_fp8_f32 when available)
__device__ __forceinline__ uint32_t pack4_fp8(float x, float y, float z, float w) {
#if HW_FP8
  int v = __builtin_amdgcn_cvt_pk_fp8_f32(x, y, 0, false);
  v = __builtin_amdgcn_cvt_pk_fp8_f32(z, w, v, true);
  return (uint32_t)v;
#else
  return f2fp8(x) | (f2fp8(y) << 8) | (f2fp8(z) << 16) | (f2fp8(w) << 24);
#endif
}

// accumulate 4 packed fp8 into two float2 accumulators (HW decode: 2 VALU ops)
__device__ __forceinline__ void acc4_fp8(uint32_t u, floatx2& a0, floatx2& a1) {
#if HW_FP8
  a0 += __builtin_amdgcn_cvt_pk_f32_fp8(u, false);
  a1 += __builtin_amdgcn_cvt_pk_f32_fp8(u, true);
#else
  a0.x += fp82f(u & 0xffu);
  a0.y += fp82f((u >> 8) & 0xffu);
  a1.x += fp82f((u >> 16) & 0xffu);
  a1.y += fp82f((u >> 24) & 0xffu);
#endif
}

// weights-only fallback converter
__global__ __launch_bounds__(256) void cvt_weights(
    const float* __restrict__ W1, const float* __restrict__ W3,
    uint16_t* __restrict__ w1b, uint16_t* __restrict__ w3b) {
  int i = blockIdx.x * 256 + threadIdx.x;
  if (i < DOUT * 2 * DFEAT) w1b[i] = (uint16_t)f2bf(W1[i]);
  if (i < NCLS * DOUT)      w3b[i] = (uint16_t)f2bf(W3[i]);
}

// fused: feat fp32 -> e4m3 table (128 MB traffic) + weights -> bf16
__global__ __launch_bounds__(256) void cvt_all(
    const float* __restrict__ feat, const float* __restrict__ W1,
    const float* __restrict__ W3, uint8_t* __restrict__ featb8,
    uint16_t* __restrict__ w1b, uint16_t* __restrict__ w3b) {
  const int b = blockIdx.x;
  if (b < FEAT_CVT_BLOCKS) {
    const size_t i = ((size_t)b * 256 + threadIdx.x) * 16;
    const float4 f0 = *(const float4*)(feat + i + 0);
    const float4 f1 = *(const float4*)(feat + i + 4);
    const float4 f2 = *(const float4*)(feat + i + 8);
    const float4 f3 = *(const float4*)(feat + i + 12);
    uint4 p;
    p.x = pack4_fp8(f0.x, f0.y, f0.z, f0.w);
    p.y = pack4_fp8(f1.x, f1.y, f1.z, f1.w);
    p.z = pack4_fp8(f2.x, f2.y, f2.z, f2.w);
    p.w = pack4_fp8(f3.x, f3.y, f3.z, f3.w);
    *(uint4*)(featb8 + i) = p;
  } else {
    const int i = (b - FEAT_CVT_BLOCKS) * 256 + threadIdx.x;
    if (i < DOUT * 2 * DFEAT) w1b[i] = (uint16_t)f2bf(W1[i]);
    if (i < NCLS * DOUT)      w3b[i] = (uint16_t)f2bf(W3[i]);
  }
}

template <bool FP8T>
__global__ __launch_bounds__(256, 8) void sage_fused(
    const int* __restrict__ inputs, const int* __restrict__ nbr,
    const float* __restrict__ feat, const uint8_t* __restrict__ featb8,
    const uint16_t* __restrict__ w1b, const float* __restrict__ b1,
    const uint16_t* __restrict__ w3b, const float* __restrict__ b3,
    float* __restrict__ out) {
  // TILE=16: embL/lgL alias (8448 B) + hL (8448 B) = 16896 B => 8 blocks/CU
  // at <=64 VGPR (launch_bounds(256,8) enforces the VGPR cap) = 100% occupancy
  __shared__ __align__(16) unsigned char smemA[TILE * 264 * 2];   // 8448 B
  __shared__ __align__(16) uint16_t hL[TILE][264];                // 8448 B
  uint16_t (*embL)[264] = (uint16_t (*)[264])smemA;
  float    (*lgL)[132]  = (float    (*)[132])smemA;

  const int tid  = threadIdx.x;
  const int w    = __builtin_amdgcn_readfirstlane(tid >> 6);   // wave 0..3
  const int lane = tid & 63;
  const int quad = lane >> 4;
  const int l16  = lane & 15;

  // ---------------- Phase 1: gather + segment-mean -> emb (bf16 in LDS) ----
  // fp8 table row = 128 B. One full-wave uint2 load (8 B/lane) covers FOUR
  // rows per VMEM instruction (lane>>4 = row slot, lane&15 = 8-dim chunk).
  // 5 wave-VMEM/node. Decode+accumulate via HW v_cvt_pk_f32_fp8 (2 ops per
  // 4 elems); two shfl_xor rounds combine the 4 row slots.
  {
    const int nodeBase = blockIdx.x * TILE + w * 4;
    if constexpr (FP8T) {
      const uint8_t* fb = featb8 + (lane & 15) * 8;   // chunk byte offset
#pragma unroll
      for (int p = 0; p < 4; p += 2) {
        const int nA = nodeBase + p, nB = nodeBase + p + 1;
        const int* nbA = nbr + nA * DEG;     // wave-uniform -> s_load
        const int* nbB = nbr + nB * DEG;
        const int sA = inputs[nA], sB = inputs[nB];
        uint2 gA[4], gB[4];
        // ---- issue both nodes' loads (10 VMEM, ~5 KB in flight) ----------
#pragma unroll
        for (int k = 0; k < 4; ++k) {
          const int i0 = nbA[4 * k + 0], i1 = nbA[4 * k + 1];
          const int i2 = nbA[4 * k + 2], i3 = nbA[4 * k + 3];
          const int lo  = (lane & 16) ? i1 : i0;
          const int hi  = (lane & 16) ? i3 : i2;
          const int rid = (lane & 32) ? hi : lo;       // row slot = lane>>4
          gA[k] = *(const uint2*)(fb + (size_t)rid * DFEAT);
        }
        const float2 svA = *(const float2*)(feat + (size_t)sA * DFEAT + lane * 2);
#pragma unroll
        for (int k = 0; k < 4; ++k) {
          const int i0 = nbB[4 * k + 0], i1 = nbB[4 * k + 1];
          const int i2 = nbB[4 * k + 2], i3 = nbB[4 * k + 3];
          const int lo  = (lane & 16) ? i1 : i0;
          const int hi  = (lane & 16) ? i3 : i2;
          const int rid = (lane & 32) ? hi : lo;
          gB[k] = *(const uint2*)(fb + (size_t)rid * DFEAT);
        }
        const float2 svB = *(const float2*)(feat + (size_t)sB * DFEAT + lane * 2);
        // ---- reduce + write, node A then node B --------------------------
#pragma unroll
        for (int nn = 0; nn < 2; ++nn) {
          const uint2* g = nn ? gB : gA;
          const float2 sv = nn ? svB : svA;
          const int row = w * 4 + p + nn;
          floatx2 q0 = {0.f, 0.f}, q1 = {0.f, 0.f};
          floatx2 q2 = {0.f, 0.f}, q3 = {0.f, 0.f};
#pragma unroll
          for (int k = 0; k < 4; ++k) {
            acc4_fp8(g[k].x, q0, q1);
            acc4_fp8(g[k].y, q2, q3);
          }
          float acc[8] = {q0.x, q0.y, q1.x, q1.y, q2.x, q2.y, q3.x, q3.y};
#pragma unroll
          for (int j = 0; j < 8; ++j) {
            acc[j] += __shfl_xor(acc[j], 16);   // combine row slots 0<->1
            acc[j] += __shfl_xor(acc[j], 32);   // combine row slots {0,1}<->{2,3}
          }
          uint4 mp;
          mp.x = f2bf(acc[0] * 0.0625f) | (f2bf(acc[1] * 0.0625f) << 16);
          mp.y = f2bf(acc[2] * 0.0625f) | (f2bf(acc[3] * 0.0625f) << 16);
          mp.z = f2bf(acc[4] * 0.0625f) | (f2bf(acc[5] * 0.0625f) << 16);
          mp.w = f2bf(acc[6] * 0.0625f) | (f2bf(acc[7] * 0.0625f) << 16);
          *(uint32_t*)&embL[row][lane * 2] = f2bf(sv.x) | (f2bf(sv.y) << 16);
          if (lane < 16)                       // lane == chunk c: dims 8c..8c+7
            *(uint4*)&embL[row][DFEAT + lane * 8] = mp;
        }
      }
    } else {
      // fp32 fallback (workspace too small): full-wave float2 rows
      const float* fb = feat + lane * 2;
#pragma unroll
      for (int p = 0; p < 4; ++p) {
        const int node = nodeBase + p;
        const int* nb  = nbr + node * DEG;
        const int self = inputs[node];
        float2 r[16];
#pragma unroll
        for (int j = 0; j < 16; ++j)
          r[j] = *(const float2*)(fb + (size_t)nb[j] * DFEAT);
        const float2 sv = *(const float2*)(fb + (size_t)self * DFEAT);
        const float sx = (((r[0].x + r[1].x) + (r[2].x + r[3].x)) + ((r[4].x + r[5].x) + (r[6].x + r[7].x)))
                       + (((r[8].x + r[9].x) + (r[10].x + r[11].x)) + ((r[12].x + r[13].x) + (r[14].x + r[15].x)));
        const float sy = (((r[0].y + r[1].y) + (r[2].y + r[3].y)) + ((r[4].y + r[5].y) + (r[6].y + r[7].y)))
                       + (((r[8].y + r[9].y) + (r[10].y + r[11].y)) + ((r[12].y + r[13].y) + (r[14].y + r[15].y)));
        const int row = w * 4 + p;
        *(uint32_t*)&embL[row][lane * 2]         = f2bf(sv.x) | (f2bf(sv.y) << 16);
        *(uint32_t*)&embL[row][DFEAT + lane * 2] = f2bf(sx * 0.0625f) | (f2bf(sy * 0.0625f) << 16);
      }
    }
  }
  __syncthreads();

  const int kq = quad * 8;

  // ---------------- Phase 2: h = relu(emb @ W1^T + b1), bf16 -> LDS --------
  // M=16 rows; wave w owns output cols w*64 .. w*64+63
  {
    floatx4 acc[4];
#pragma unroll
    for (int ot = 0; ot < 4; ++ot) {
      floatx4 z = {0.f, 0.f, 0.f, 0.f};
      acc[ot] = z;
    }
#pragma unroll
    for (int kt = 0; kt < 8; ++kt) {
      const int k0 = kt * 32 + kq;
      const bf16x8 a = *(const bf16x8*)&embL[l16][k0];
#pragma unroll
      for (int ot = 0; ot < 4; ++ot) {
        const int o = w * 64 + ot * 16 + l16;
        const bf16x8 b = *(const bf16x8*)(w1b + o * 256 + k0);
        acc[ot] = __builtin_amdgcn_mfma_f32_16x16x32_bf16(a, b, acc[ot], 0, 0, 0);
      }
    }
#pragma unroll
    for (int ot = 0; ot < 4; ++ot) {
      const int o = w * 64 + ot * 16 + l16;
      const float bias = b1[o];
#pragma unroll
      for (int r = 0; r < 4; ++r) {
        float v = acc[ot][r] + bias;
        v = fmaxf(v, 0.f);
        hL[quad * 4 + r][o] = (uint16_t)f2bf(v);
      }
    }
  }
  __syncthreads();

  // ---------------- Phase 3: logits = h @ W3^T + b3 -> LDS fp32 ------------
  {
    floatx4 acc2[2];
#pragma unroll
    for (int ct = 0; ct < 2; ++ct) {
      floatx4 z = {0.f, 0.f, 0.f, 0.f};
      acc2[ct] = z;
    }
#pragma unroll
    for (int kt = 0; kt < 8; ++kt) {
      const int k0 = kt * 32 + kq;
      const bf16x8 a = *(const bf16x8*)&hL[l16][k0];
#pragma unroll
      for (int ct = 0; ct < 2; ++ct) {
        const int c = w * 32 + ct * 16 + l16;
        const bf16x8 b = *(const bf16x8*)(w3b + c * 256 + k0);
        acc2[ct] = __builtin_amdgcn_mfma_f32_16x16x32_bf16(a, b, acc2[ct], 0, 0, 0);
      }
    }
#pragma unroll
    for (int ct = 0; ct < 2; ++ct) {
      const int c = w * 32 + ct * 16 + l16;
      const float bias = b3[c];
#pragma unroll
      for (int r = 0; r < 4; ++r)
        lgL[quad * 4 + r][c] = acc2[ct][r] + bias;
    }
  }
  __syncthreads();

  // ---------------- Phase 4: row L2-normalize + store ----------------------
  {
    const int nr  = tid >> 4;       // node row 0..15
    const int sub = tid & 15;       // 16 threads per row, 8 cols each
    const float* lrow = &lgL[nr][sub * 8];
    float4 v0 = *(const float4*)(lrow + 0);
    float4 v1 = *(const float4*)(lrow + 4);
    float ss = v0.x * v0.x + v0.y * v0.y + v0.z * v0.z + v0.w * v0.w
             + v1.x * v1.x + v1.y * v1.y + v1.z * v1.z + v1.w * v1.w;
    ss += __shfl_xor(ss, 1);
    ss += __shfl_xor(ss, 2);
    ss += __shfl_xor(ss, 4);
    ss += __shfl_xor(ss, 8);
    const float scale = 1.f / fmaxf(sqrtf(ss), 1e-12f);
    v0.x *= scale; v0.y *= scale; v0.z *= scale; v0.w *= scale;
    v1.x *= scale; v1.y *= scale; v1.z *= scale; v1.w *= scale;
    float* op = out + ((size_t)(blockIdx.x * TILE + nr)) * NCLS + sub * 8;
    *(float4*)(op + 0) = v0;
    *(float4*)(op + 4) = v1;
  }
}

extern "C" void kernel_launch(void* const* d_in, const int* in_sizes, int n_in,
                              void* d_out, int out_size, void* d_ws, size_t ws_size,
                              hipStream_t stream) {
  const int*   inputs = (const int*)d_in[0];
  const int*   nbr    = (const int*)d_in[1];
  // d_in[2] segment_ids: regular repeat(arange(B), 16) -> implicit, unused
  const float* feat   = (const float*)d_in[3];
  const float* W1     = (const float*)d_in[4];
  const float* b1     = (const float*)d_in[5];
  const float* W3     = (const float*)d_in[6];
  const float* b3     = (const float*)d_in[7];

  uint16_t* w1b    = (uint16_t*)d_ws;               // 256*256 bf16 = 128 KiB
  uint16_t* w3b    = w1b + DOUT * 2 * DFEAT;        // 128*256 bf16 =  64 KiB
  uint8_t*  featb8 = (uint8_t*)(w3b + NCLS * DOUT); // 200000*128 e4m3 = 25.6 MB

  const size_t need = (size_t)(DOUT * 2 * DFEAT + NCLS * DOUT) * sizeof(uint16_t)
                    + (size_t)NNODES * DFEAT;

  if (ws_size >= need) {
    cvt_all<<<FEAT_CVT_BLOCKS + (DOUT * 2 * DFEAT) / 256, 256, 0, stream>>>(
        feat, W1, W3, featb8, w1b, w3b);
    sage_fused<true><<<BNODES / TILE, 256, 0, stream>>>(
        inputs, nbr, feat, featb8, w1b, b1, w3b, b3, (float*)d_out);
  } else {
    cvt_weights<<<(DOUT * 2 * DFEAT) / 256, 256, 0, stream>>>(W1, W3, w1b, w3b);
    sage_fused<false><<<BNODES / TILE, 256, 0, stream>>>(
        inputs, nbr, feat, nullptr, w1b, b1, w3b, b3, (float*)d_out);
  }
}